// Round 1
// baseline (1944.306 us; speedup 1.0000x reference)
//
#include <hip/hip_runtime.h>

#define N_PTS   65536
#define HID     256
#define PTS     2            // points per wave
#define WAVES   4            // waves per block
#define BLOCK   (WAVES * 64)
#define NCH     5            // v, gx, gy, hxx, hyy
#define NBLOCKS (N_PTS / (PTS * WAVES))   // 8192

__device__ __forceinline__ float fast_tanh(float x) {
    float e = __expf(2.0f * x);
    return 1.0f - 2.0f / (e + 1.0f);
}

__global__ __launch_bounds__(BLOCK) void pinn_main(
    const float* __restrict__ vect, const int* __restrict__ vals,
    const float* __restrict__ W0, const float* __restrict__ b0,
    const float* __restrict__ W1, const float* __restrict__ b1,
    const float* __restrict__ W2, const float* __restrict__ b2,
    const float* __restrict__ W3, const float* __restrict__ b3,
    const float* __restrict__ W4, const float* __restrict__ b4,
    const float* __restrict__ W5, const float* __restrict__ b5,
    float* __restrict__ partials)
{
    __shared__ float lds[WAVES][PTS * NCH][HID];
    __shared__ float red[WAVES][5];

    const int tid   = threadIdx.x;
    const int wave  = tid >> 6;
    const int lane  = tid & 63;
    const int pbase = (blockIdx.x * WAVES + wave) * PTS;
    const int j0    = lane * 4;

    float (*hl)[HID] = lds[wave];

    // ---------- layer 0: 2 -> 256 ----------
    {
        float4 wx4 = *(const float4*)(W0 + j0);        // W0[0][j0..j0+3]
        float4 wy4 = *(const float4*)(W0 + HID + j0);  // W0[1][j0..j0+3]
        float4 bb4 = *(const float4*)(b0 + j0);
        float wx[4] = {wx4.x, wx4.y, wx4.z, wx4.w};
        float wy[4] = {wy4.x, wy4.y, wy4.z, wy4.w};
        float bb[4] = {bb4.x, bb4.y, bb4.z, bb4.w};
        for (int pt = 0; pt < PTS; ++pt) {
            float x = vect[(pbase + pt) * 2 + 0];
            float y = vect[(pbase + pt) * 2 + 1];
            #pragma unroll
            for (int q = 0; q < 4; ++q) {
                float z   = x * wx[q] + y * wy[q] + bb[q];
                float v   = fast_tanh(z);
                float s   = 1.0f - v * v;
                float gx  = s * wx[q];
                float gy  = s * wy[q];
                float hxx = -2.0f * v * gx * wx[q];    // s*0 - 2 v s wx^2
                float hyy = -2.0f * v * gy * wy[q];
                hl[pt * NCH + 0][j0 + q] = v;
                hl[pt * NCH + 1][j0 + q] = gx;
                hl[pt * NCH + 2][j0 + q] = gy;
                hl[pt * NCH + 3][j0 + q] = hxx;
                hl[pt * NCH + 4][j0 + q] = hyy;
            }
        }
    }

    // ---------- hidden layers 1..4: 256 -> 256 ----------
    const float* Ws[4] = {W1, W2, W3, W4};
    const float* bs[4] = {b1, b2, b3, b4};

    for (int L = 0; L < 4; ++L) {
        const float* __restrict__ wp = Ws[L] + j0;
        float acc[PTS][NCH][4];
        #pragma unroll
        for (int pt = 0; pt < PTS; ++pt)
            #pragma unroll
            for (int ch = 0; ch < NCH; ++ch)
                #pragma unroll
                for (int q = 0; q < 4; ++q) acc[pt][ch][q] = 0.0f;

        __syncthreads();   // previous layer's writes visible

        #pragma unroll 4
        for (int i = 0; i < HID; ++i) {
            float4 w = *(const float4*)(wp + i * HID);
            float wv[4] = {w.x, w.y, w.z, w.w};
            #pragma unroll
            for (int pt = 0; pt < PTS; ++pt) {
                #pragma unroll
                for (int ch = 0; ch < NCH; ++ch) {
                    float h = hl[pt * NCH + ch][i];
                    #pragma unroll
                    for (int q = 0; q < 4; ++q)
                        acc[pt][ch][q] += h * wv[q];
                }
            }
        }

        float4 bb4 = *(const float4*)(bs[L] + j0);
        float bb[4] = {bb4.x, bb4.y, bb4.z, bb4.w};

        __syncthreads();   // all reads of old h done before overwrite

        #pragma unroll
        for (int pt = 0; pt < PTS; ++pt) {
            #pragma unroll
            for (int q = 0; q < 4; ++q) {
                float z   = acc[pt][0][q] + bb[q];
                float v   = fast_tanh(z);
                float s   = 1.0f - v * v;
                float zgx = acc[pt][1][q];
                float zgy = acc[pt][2][q];
                float gx  = s * zgx;
                float gy  = s * zgy;
                float hxx = s * acc[pt][3][q] - 2.0f * v * gx * zgx;
                float hyy = s * acc[pt][4][q] - 2.0f * v * gy * zgy;
                hl[pt * NCH + 0][j0 + q] = v;
                hl[pt * NCH + 1][j0 + q] = gx;
                hl[pt * NCH + 2][j0 + q] = gy;
                hl[pt * NCH + 3][j0 + q] = hxx;
                hl[pt * NCH + 4][j0 + q] = hyy;
            }
        }
    }

    __syncthreads();

    // ---------- final layer 256 -> 1 + per-point loss terms ----------
    float sT[PTS] = {0.0f, 0.0f};
    float sR[PTS] = {0.0f, 0.0f};
    #pragma unroll
    for (int r = 0; r < 4; ++r) {
        int   i  = lane + 64 * r;
        float w5 = W5[i];
        #pragma unroll
        for (int pt = 0; pt < PTS; ++pt) {
            sT[pt] += hl[pt * NCH + 0][i] * w5;
            sR[pt] += (hl[pt * NCH + 3][i] + hl[pt * NCH + 4][i]) * w5;
        }
    }
    #pragma unroll
    for (int pt = 0; pt < PTS; ++pt) {
        sT[pt] += __shfl_down(sT[pt], 32, 64);
        sR[pt] += __shfl_down(sR[pt], 32, 64);
        sT[pt] += __shfl_down(sT[pt], 16, 64);
        sR[pt] += __shfl_down(sR[pt], 16, 64);
        sT[pt] += __shfl_down(sT[pt], 8, 64);
        sR[pt] += __shfl_down(sR[pt], 8, 64);
        sT[pt] += __shfl_down(sT[pt], 4, 64);
        sR[pt] += __shfl_down(sR[pt], 4, 64);
        sT[pt] += __shfl_down(sT[pt], 2, 64);
        sR[pt] += __shfl_down(sR[pt], 2, 64);
        sT[pt] += __shfl_down(sT[pt], 1, 64);
        sR[pt] += __shfl_down(sR[pt], 1, 64);
    }

    if (lane == 0) {
        float r0 = 0.f, r1 = 0.f, r2 = 0.f, r3 = 0.f, r4 = 0.f;
        float bias5 = b5[0];
        for (int pt = 0; pt < PTS; ++pt) {
            float T = sT[pt] + bias5;
            float R = sR[pt];
            r0 += R * R;
            int m = vals[pbase + pt];
            if (m == 1)      { float d = T - 1200.0f; r1 += d * d; r2 += 1.0f; }
            else if (m == 2) { float d = T - 25.0f;   r3 += d * d; r4 += 1.0f; }
        }
        red[wave][0] = r0; red[wave][1] = r1; red[wave][2] = r2;
        red[wave][3] = r3; red[wave][4] = r4;
    }
    __syncthreads();
    if (tid == 0) {
        #pragma unroll
        for (int c = 0; c < 5; ++c) {
            float s = red[0][c] + red[1][c] + red[2][c] + red[3][c];
            partials[blockIdx.x * 5 + c] = s;
        }
    }
}

__global__ __launch_bounds__(256) void pinn_reduce(const float* __restrict__ p,
                                                   float* __restrict__ out)
{
    float s[5] = {0.f, 0.f, 0.f, 0.f, 0.f};
    for (int idx = threadIdx.x; idx < NBLOCKS; idx += 256) {
        #pragma unroll
        for (int c = 0; c < 5; ++c) s[c] += p[idx * 5 + c];
    }
    #pragma unroll
    for (int c = 0; c < 5; ++c) {
        s[c] += __shfl_down(s[c], 32, 64);
        s[c] += __shfl_down(s[c], 16, 64);
        s[c] += __shfl_down(s[c], 8, 64);
        s[c] += __shfl_down(s[c], 4, 64);
        s[c] += __shfl_down(s[c], 2, 64);
        s[c] += __shfl_down(s[c], 1, 64);
    }
    __shared__ float r[4][5];
    int wave = threadIdx.x >> 6;
    int lane = threadIdx.x & 63;
    if (lane == 0) {
        #pragma unroll
        for (int c = 0; c < 5; ++c) r[wave][c] = s[c];
    }
    __syncthreads();
    if (threadIdx.x == 0) {
        float t[5];
        #pragma unroll
        for (int c = 0; c < 5; ++c) t[c] = r[0][c] + r[1][c] + r[2][c] + r[3][c];
        float loss = t[0] / (float)N_PTS
                   + t[1] / fmaxf(t[2], 1.0f)
                   + t[3] / fmaxf(t[4], 1.0f);
        out[0] = loss;
    }
}

extern "C" void kernel_launch(void* const* d_in, const int* in_sizes, int n_in,
                              void* d_out, int out_size, void* d_ws, size_t ws_size,
                              hipStream_t stream) {
    const float* vect = (const float*)d_in[0];
    const int*   vals = (const int*)d_in[1];
    const float* W0 = (const float*)d_in[2];
    const float* b0 = (const float*)d_in[3];
    const float* W1 = (const float*)d_in[4];
    const float* b1 = (const float*)d_in[5];
    const float* W2 = (const float*)d_in[6];
    const float* b2 = (const float*)d_in[7];
    const float* W3 = (const float*)d_in[8];
    const float* b3 = (const float*)d_in[9];
    const float* W4 = (const float*)d_in[10];
    const float* b4 = (const float*)d_in[11];
    const float* W5 = (const float*)d_in[12];
    const float* b5 = (const float*)d_in[13];

    float* partials = (float*)d_ws;           // NBLOCKS * 5 floats = 160 KB
    float* out      = (float*)d_out;

    pinn_main<<<NBLOCKS, BLOCK, 0, stream>>>(vect, vals, W0, b0, W1, b1, W2, b2,
                                             W3, b3, W4, b4, W5, b5, partials);
    pinn_reduce<<<1, 256, 0, stream>>>(partials, out);
}

// Round 2
// 296.966 us; speedup vs baseline: 6.5472x; 6.5472x over previous
//
#include <hip/hip_runtime.h>

#define N_PTS   65536
#define PBLK    16                 // points per block
#define NBLK    (N_PTS / PBLK)     // 4096 blocks
#define HID     256

typedef __attribute__((ext_vector_type(8))) short short8;   // 8 bf16 = 4 VGPR
typedef __attribute__((ext_vector_type(4))) short short4v;  // 4 bf16 = 8 B
typedef __attribute__((ext_vector_type(4))) float floatx4;  // MFMA C/D

__device__ __forceinline__ short f2bf(float x) {            // RNE float->bf16
    union { float f; unsigned u; } v; v.f = x;
    unsigned r = v.u + 0x7FFFu + ((v.u >> 16) & 1u);
    return (short)(r >> 16);
}
__device__ __forceinline__ float bf2f(short h) {
    union { unsigned u; float f; } v;
    v.u = ((unsigned)(unsigned short)h) << 16;
    return v.f;
}
__device__ __forceinline__ float fast_tanh(float x) {
    float e = __expf(2.0f * x);
    return 1.0f - 2.0f / (e + 1.0f);
}

// ---- weight transpose+convert: Wt[L][n][k] = bf16(W_L[k][n]) ----
__global__ __launch_bounds__(256) void conv_w(
    const float* __restrict__ W1, const float* __restrict__ W2,
    const float* __restrict__ W3, const float* __restrict__ W4,
    short* __restrict__ Wt)
{
    int layer = blockIdx.x >> 8;
    int n     = blockIdx.x & 255;
    const float* W = (layer == 0) ? W1 : (layer == 1) ? W2 : (layer == 2) ? W3 : W4;
    int k = threadIdx.x;
    Wt[((layer << 8) + n) * 256 + k] = f2bf(W[k * 256 + n]);
}

__global__ __launch_bounds__(256, 3) void pinn_main(
    const float* __restrict__ vect, const int* __restrict__ vals,
    const float* __restrict__ W0, const float* __restrict__ b0,
    const float* __restrict__ b1, const float* __restrict__ b2,
    const float* __restrict__ b3, const float* __restrict__ b4,
    const float* __restrict__ W5, const float* __restrict__ b5,
    const short* __restrict__ Wt, float* __restrict__ partials)
{
    // H[ch][pt][k] bf16, col-swizzled:  idx = ch*4096 + pt*256 + (k ^ ((pt&7)<<3))
    __shared__ __align__(16) short Hs[5 * PBLK * HID];   // 40 KB
    __shared__ float red[4][5];

    const int tid   = threadIdx.x;
    const int wave  = tid >> 6;
    const int lane  = tid & 63;
    const int g     = lane >> 4;          // lane group 0..3
    const int l15   = lane & 15;
    const int pbase = blockIdx.x * PBLK;

    // ---------------- layer 0: 2 -> 256 (fp32 VALU, cheap) ----------------
    {
        const int c0 = lane * 4;
        float4 wx4 = *(const float4*)(W0 + c0);          // W0[0][c]
        float4 wy4 = *(const float4*)(W0 + HID + c0);    // W0[1][c]
        float4 bb4 = *(const float4*)(b0 + c0);
        float wx[4] = {wx4.x, wx4.y, wx4.z, wx4.w};
        float wy[4] = {wy4.x, wy4.y, wy4.z, wy4.w};
        float bb[4] = {bb4.x, bb4.y, bb4.z, bb4.w};
        #pragma unroll
        for (int p = 0; p < 4; ++p) {
            int pt = 4 * wave + p;
            float x = vect[(pbase + pt) * 2 + 0];
            float y = vect[(pbase + pt) * 2 + 1];
            short4v hv, hgx, hgy, hxx, hyy;
            #pragma unroll
            for (int q = 0; q < 4; ++q) {
                float z  = x * wx[q] + y * wy[q] + bb[q];
                float a  = fast_tanh(z);
                float s  = 1.0f - a * a;
                float gx = s * wx[q];
                float gy = s * wy[q];
                hv[q]  = f2bf(a);
                hgx[q] = f2bf(gx);
                hgy[q] = f2bf(gy);
                hxx[q] = f2bf(-2.0f * a * gx * wx[q]);
                hyy[q] = f2bf(-2.0f * a * gy * wy[q]);
            }
            int idx = pt * 256 + (c0 ^ ((pt & 7) << 3));
            *(short4v*)&Hs[0 * 4096 + idx] = hv;
            *(short4v*)&Hs[1 * 4096 + idx] = hgx;
            *(short4v*)&Hs[2 * 4096 + idx] = hgy;
            *(short4v*)&Hs[3 * 4096 + idx] = hxx;
            *(short4v*)&Hs[4 * 4096 + idx] = hyy;
        }
    }

    // ---------------- hidden layers 1..4 via MFMA ----------------
    const float* bs[4] = {b1, b2, b3, b4};
    const int pt_a = l15;                      // A-frag row (point)
    const int swzA = (pt_a & 7) << 3;

    #pragma unroll
    for (int L = 0; L < 4; ++L) {
        floatx4 acc[5][4];
        #pragma unroll
        for (int ch = 0; ch < 5; ++ch)
            #pragma unroll
            for (int cf = 0; cf < 4; ++cf)
                acc[ch][cf] = (floatx4){0.f, 0.f, 0.f, 0.f};

        const short* wtb = Wt + L * 65536 + (l15 + 64 * wave) * 256 + g * 8;

        __syncthreads();   // H writes from previous stage visible

        #pragma unroll
        for (int ks = 0; ks < 8; ++ks) {
            const int ka = (ks * 32 + g * 8) ^ swzA;   // swizzled A col start
            short8 af[5], bf[4];
            #pragma unroll
            for (int ch = 0; ch < 5; ++ch)
                af[ch] = *(const short8*)&Hs[ch * 4096 + pt_a * 256 + ka];
            #pragma unroll
            for (int cf = 0; cf < 4; ++cf)
                bf[cf] = *(const short8*)(wtb + cf * 4096 + ks * 32);
            #pragma unroll
            for (int ch = 0; ch < 5; ++ch)
                #pragma unroll
                for (int cf = 0; cf < 4; ++cf)
                    acc[ch][cf] = __builtin_amdgcn_mfma_f32_16x16x32_bf16(
                        af[ch], bf[cf], acc[ch][cf], 0, 0, 0);
        }

        __syncthreads();   // all reads of H done before overwrite

        #pragma unroll
        for (int cf = 0; cf < 4; ++cf) {
            const int n  = l15 + 16 * cf + 64 * wave;
            const float bb = bs[L][n];
            #pragma unroll
            for (int r = 0; r < 4; ++r) {
                const int pt = 4 * g + r;
                float z   = acc[0][cf][r] + bb;
                float a   = fast_tanh(z);
                float s   = 1.0f - a * a;
                float zgx = acc[1][cf][r];
                float zgy = acc[2][cf][r];
                float gx  = s * zgx;
                float gy  = s * zgy;
                float xx  = s * acc[3][cf][r] - 2.0f * a * gx * zgx;
                float yy  = s * acc[4][cf][r] - 2.0f * a * gy * zgy;
                int base = pt * 256 + (n ^ ((pt & 7) << 3));
                Hs[0 * 4096 + base] = f2bf(a);
                Hs[1 * 4096 + base] = f2bf(gx);
                Hs[2 * 4096 + base] = f2bf(gy);
                Hs[3 * 4096 + base] = f2bf(xx);
                Hs[4 * 4096 + base] = f2bf(yy);
            }
        }
    }

    __syncthreads();

    // ---------------- final layer 256 -> 1 + loss terms ----------------
    float r0 = 0.f, r1 = 0.f, r2 = 0.f, r3 = 0.f, r4 = 0.f;
    const float bias5 = b5[0];
    const int c0 = lane * 4;
    float4 w54 = *(const float4*)(W5 + c0);
    float w5[4] = {w54.x, w54.y, w54.z, w54.w};

    #pragma unroll
    for (int sub = 0; sub < 4; ++sub) {
        int pt  = 4 * wave + sub;
        int idx = pt * 256 + (c0 ^ ((pt & 7) << 3));
        short4v hv = *(const short4v*)&Hs[0 * 4096 + idx];
        short4v hx = *(const short4v*)&Hs[3 * 4096 + idx];
        short4v hy = *(const short4v*)&Hs[4 * 4096 + idx];
        float sT = 0.f, sR = 0.f;
        #pragma unroll
        for (int q = 0; q < 4; ++q) {
            sT += bf2f(hv[q]) * w5[q];
            sR += (bf2f(hx[q]) + bf2f(hy[q])) * w5[q];
        }
        #pragma unroll
        for (int off = 32; off > 0; off >>= 1) {
            sT += __shfl_down(sT, off, 64);
            sR += __shfl_down(sR, off, 64);
        }
        if (lane == 0) {
            float T = sT + bias5;
            r0 += sR * sR;
            int m = vals[pbase + pt];
            if (m == 1)      { float d = T - 1200.0f; r1 += d * d; r2 += 1.0f; }
            else if (m == 2) { float d = T - 25.0f;   r3 += d * d; r4 += 1.0f; }
        }
    }

    if (lane == 0) {
        red[wave][0] = r0; red[wave][1] = r1; red[wave][2] = r2;
        red[wave][3] = r3; red[wave][4] = r4;
    }
    __syncthreads();
    if (tid == 0) {
        #pragma unroll
        for (int c = 0; c < 5; ++c)
            partials[blockIdx.x * 5 + c] =
                red[0][c] + red[1][c] + red[2][c] + red[3][c];
    }
}

__global__ __launch_bounds__(256) void pinn_reduce(const float* __restrict__ p,
                                                   float* __restrict__ out)
{
    float s[5] = {0.f, 0.f, 0.f, 0.f, 0.f};
    for (int idx = threadIdx.x; idx < NBLK; idx += 256) {
        #pragma unroll
        for (int c = 0; c < 5; ++c) s[c] += p[idx * 5 + c];
    }
    #pragma unroll
    for (int c = 0; c < 5; ++c) {
        #pragma unroll
        for (int off = 32; off > 0; off >>= 1)
            s[c] += __shfl_down(s[c], off, 64);
    }
    __shared__ float r[4][5];
    int wave = threadIdx.x >> 6;
    int lane = threadIdx.x & 63;
    if (lane == 0) {
        #pragma unroll
        for (int c = 0; c < 5; ++c) r[wave][c] = s[c];
    }
    __syncthreads();
    if (threadIdx.x == 0) {
        float t[5];
        #pragma unroll
        for (int c = 0; c < 5; ++c) t[c] = r[0][c] + r[1][c] + r[2][c] + r[3][c];
        out[0] = t[0] / (float)N_PTS
               + t[1] / fmaxf(t[2], 1.0f)
               + t[3] / fmaxf(t[4], 1.0f);
    }
}

extern "C" void kernel_launch(void* const* d_in, const int* in_sizes, int n_in,
                              void* d_out, int out_size, void* d_ws, size_t ws_size,
                              hipStream_t stream) {
    const float* vect = (const float*)d_in[0];
    const int*   vals = (const int*)d_in[1];
    const float* W0 = (const float*)d_in[2];
    const float* b0 = (const float*)d_in[3];
    const float* W1 = (const float*)d_in[4];
    const float* b1 = (const float*)d_in[5];
    const float* W2 = (const float*)d_in[6];
    const float* b2 = (const float*)d_in[7];
    const float* W3 = (const float*)d_in[8];
    const float* b3 = (const float*)d_in[9];
    const float* W4 = (const float*)d_in[10];
    const float* b4 = (const float*)d_in[11];
    const float* W5 = (const float*)d_in[12];
    const float* b5 = (const float*)d_in[13];

    float* partials = (float*)d_ws;                        // 4096*5*4 = 80 KB
    short* Wt       = (short*)((char*)d_ws + 131072);      // 4*256*256*2 = 512 KB
    float* out      = (float*)d_out;

    conv_w<<<1024, 256, 0, stream>>>(W1, W2, W3, W4, Wt);
    pinn_main<<<NBLK, 256, 0, stream>>>(vect, vals, W0, b0, b1, b2, b3, b4,
                                        W5, b5, Wt, partials);
    pinn_reduce<<<1, 256, 0, stream>>>(partials, out);
}